// Round 8
// baseline (191.776 us; speedup 1.0000x reference)
//
#include <hip/hip_runtime.h>
#include <math.h>

// B=8, T=1024, E=1024, H=16 heads x 64 dim. All GEMMs: M=8192, N=K=1024.
// Pipeline:
//   cast xq,xkv -> bf16 ; transpose+cast weights -> [N][K] bf16
//   build rope table (t,i)->(cos,sin)
//   fused QKV GEMM: counted-vmcnt pipelined 128x128/BK32 kernel (gemm8<0>),
//     RoPE via table in epilogue
//   flash attention, swapped-QK^T 32x32x16 MFMA, fixed-max exp2 softmax,
//     hb-fastest block remap for per-XCD KV L2 reuse
//   out = Oatt @ Wo^T (gemm8<1>, f32 out)

typedef __attribute__((ext_vector_type(8))) short bf16x8;
typedef __attribute__((ext_vector_type(4))) float f32x4;
typedef __attribute__((ext_vector_type(16))) float f32x16;

#define LOG2E 1.44269504f
#define QSCALE (0.125f * LOG2E)

__device__ __forceinline__ ushort f2bf(float f) {
    union { float f; uint32_t u; } v; v.f = f;
    uint32_t r = (v.u + 0x7FFF + ((v.u >> 16) & 1)) >> 16;
    return (ushort)r;
}
__device__ __forceinline__ uint cvt_pk_bf16(float a, float b) {
    uint r;
    asm("v_cvt_pk_bf16_f32 %0, %1, %2" : "=v"(r) : "v"(a), "v"(b));
    return r;
}
__device__ __forceinline__ float bf2f(ushort u) {
    union { uint32_t u; float f; } v; v.u = ((uint32_t)u) << 16;
    return v.f;
}

__device__ __forceinline__ void gload16(const ushort* g, ushort* l) {
    __builtin_amdgcn_global_load_lds(
        (const __attribute__((address_space(1))) unsigned int*)g,
        (__attribute__((address_space(3))) unsigned int*)l, 16, 0, 0);
}

// ---------------------------------------------------------------------------
// rope table: tbl[t*32+i] = (cos(t*f_i), sin(t*f_i)), f_i = 10000^(-i/32)
// ---------------------------------------------------------------------------
__global__ void build_rope_tbl(float2* __restrict__ tbl)
{
    int idx = blockIdx.x * 256 + threadIdx.x;   // 0..32767
    int t = idx >> 5, i = idx & 31;
    float inv_freq = exp2f(-(float)i * (13.28771238f / 32.0f));
    float s, c;
    sincosf((float)t * inv_freq, &s, &c);
    tbl[idx] = make_float2(c, s);
}

// ---------------------------------------------------------------------------
// cast f32 -> bf16, 8 elements/thread; grid.y selects (xq->Aq)/(xkv->Akv)
// ---------------------------------------------------------------------------
__global__ void cast_bf16_2(const float* __restrict__ X0, ushort* __restrict__ Y0,
                            const float* __restrict__ X1, ushort* __restrict__ Y1)
{
    const float* X = blockIdx.y ? X1 : X0;
    ushort* Y = blockIdx.y ? Y1 : Y0;
    int i = blockIdx.x * 256 + threadIdx.x;
    float4 a = ((const float4*)X)[2 * i];
    float4 b = ((const float4*)X)[2 * i + 1];
    union { float4 f; ushort u[8]; } o;
    o.u[0] = f2bf(a.x); o.u[1] = f2bf(a.y); o.u[2] = f2bf(a.z); o.u[3] = f2bf(a.w);
    o.u[4] = f2bf(b.x); o.u[5] = f2bf(b.y); o.u[6] = f2bf(b.z); o.u[7] = f2bf(b.w);
    ((float4*)Y)[i] = o.f;
}

// ---------------------------------------------------------------------------
// W [1024][1024] f32 -> Wt [1024][1024] bf16, Wt[n][k] = W[k][n]; z selects
// ---------------------------------------------------------------------------
__global__ void transpose_cast_4(const float* __restrict__ w0, ushort* __restrict__ t0,
                                 const float* __restrict__ w1, ushort* __restrict__ t1,
                                 const float* __restrict__ w2, ushort* __restrict__ t2,
                                 const float* __restrict__ w3, ushort* __restrict__ t3)
{
    const int z = blockIdx.z;
    const float* W = (z == 0) ? w0 : (z == 1) ? w1 : (z == 2) ? w2 : w3;
    ushort* Wt = (z == 0) ? t0 : (z == 1) ? t1 : (z == 2) ? t2 : t3;
    __shared__ float t[32][33];
    int bx = blockIdx.x * 32, by = blockIdx.y * 32;
    int tx = threadIdx.x, ty = threadIdx.y;   // (32,8)
#pragma unroll
    for (int e = 0; e < 32; e += 8)
        t[ty + e][tx] = W[(size_t)(by + ty + e) * 1024 + bx + tx];
    __syncthreads();
#pragma unroll
    for (int e = 0; e < 32; e += 8)
        Wt[(size_t)(bx + ty + e) * 1024 + by + tx] = f2bf(t[tx][ty + e]);
}

// ---------------------------------------------------------------------------
// Pipelined GEMM (T3+T4): C = A @ Bt^T, 128x128 tile, BK=32.
// 128 threads = 2 waves; wave covers 128 rows x 64 cols (M_rep=8, N_rep=4).
// 2 LDS buffers (A 8K + B 8K each = 32 KB total) -> 4 blocks/CU.
// Steady-state K-loop: ds-read tile->regs; lgkm0; barrier; stage tile t+2
// into same buf; 32 MFMA; vmcnt(8) (tile t+1 landed, t+2 in flight); barrier.
// T2 swizzle S(x)=x^((x>>3)&0x30) via pre-swizzled global source (linear
// gload_lds dest) + swizzled ds_read addresses.
// MODE 0: fused QKV (3 mats, bf16 out, RoPE epilogue for Q/K).
// MODE 1: out-projection (f32 out).
// ---------------------------------------------------------------------------
template <int MODE>
__global__ __launch_bounds__(128, 2)
void gemm8(const ushort* __restrict__ Aq, const ushort* __restrict__ Akv,
           const ushort* __restrict__ Wt, void* __restrict__ Out,
           const float2* __restrict__ tbl)
{
    const int K = 1024, N = 1024;
    __shared__ ushort lds[2][8192];   // per buf: A [0,4096) us, B [4096,8192)

    const int tid = threadIdx.x;
    const int w = tid >> 6, l = tid & 63;

    // bijective XCD swizzle (gridDim.x divisible by 8)
    const int id = (blockIdx.x & 7) * (gridDim.x >> 3) + (blockIdx.x >> 3);
    int mat, rt, ct;
    if (MODE == 0) { mat = id >> 9; int rem = id & 511; rt = rem >> 3; ct = rem & 7; }
    else           { mat = 0; rt = id >> 3; ct = id & 7; }
    const int row0 = rt * 128, col0 = ct * 128;

    const ushort* A  = (MODE == 0) ? (mat ? Akv : Aq) : Aq;
    const ushort* Bt = Wt + (size_t)mat * 1048576;

    // staging sources: thread's linear LDS dest D -> logical L = S(D)
    const ushort* ag[4];
    const ushort* bg[4];
#pragma unroll
    for (int i = 0; i < 4; ++i) {
        int D = tid * 16 + i * 2048;
        int L = D ^ ((D >> 3) & 0x30);
        int row = L >> 6, colb = L & 63;
        ag[i] = A  + (size_t)(row0 + row) * K + (colb >> 1);
        bg[i] = Bt + (size_t)(col0 + row) * K + (colb >> 1);
    }

    // swizzled read offsets (ushort units within tile)
    int rdA[8], rdB[4];
#pragma unroll
    for (int fm = 0; fm < 8; ++fm) {
        int byte = (fm * 16 + (l & 15)) * 64 + (l >> 4) * 16;
        rdA[fm] = (byte ^ ((byte >> 3) & 0x30)) >> 1;
    }
#pragma unroll
    for (int fn = 0; fn < 4; ++fn) {
        int byte = (w * 64 + fn * 16 + (l & 15)) * 64 + (l >> 4) * 16;
        rdB[fn] = (byte ^ ((byte >> 3) & 0x30)) >> 1;
    }

    f32x4 acc[8][4];
#pragma unroll
    for (int i = 0; i < 8; ++i)
#pragma unroll
        for (int j = 0; j < 4; ++j) acc[i][j] = (f32x4)0.f;

    bf16x8 af[8], bfr[4];

    auto STAGE = [&](int buf, int kt) {
        ushort* La = &lds[buf][0];
#pragma unroll
        for (int i = 0; i < 4; ++i) {
            gload16(ag[i] + kt * 32, La + w * 512 + i * 1024);
            gload16(bg[i] + kt * 32, La + 4096 + w * 512 + i * 1024);
        }
    };
    auto LOADFRAGS = [&](int buf) {
#pragma unroll
        for (int fm = 0; fm < 8; ++fm)
            af[fm] = *(const bf16x8*)&lds[buf][rdA[fm]];
#pragma unroll
        for (int fn = 0; fn < 4; ++fn)
            bfr[fn] = *(const bf16x8*)&lds[buf][4096 + rdB[fn]];
    };
    auto MFMA_ALL = [&]() {
#pragma unroll
        for (int fm = 0; fm < 8; ++fm)
#pragma unroll
            for (int fn = 0; fn < 4; ++fn)
                acc[fm][fn] = __builtin_amdgcn_mfma_f32_16x16x32_bf16(
                    af[fm], bfr[fn], acc[fm][fn], 0, 0, 0);
    };

    // prologue: tiles 0,1 staged; wait tile 0 (8 of 16 outstanding)
    STAGE(0, 0);
    STAGE(1, 1);
    asm volatile("s_waitcnt vmcnt(8)" ::: "memory");
    __builtin_amdgcn_sched_barrier(0);
    __builtin_amdgcn_s_barrier();

#pragma unroll 2
    for (int t2 = 0; t2 < 30; ++t2) {
        const int b = t2 & 1;
        LOADFRAGS(b);
        asm volatile("s_waitcnt lgkmcnt(0)" ::: "memory");
        __builtin_amdgcn_sched_barrier(0);
        __builtin_amdgcn_s_barrier();       // all waves consumed buf b
        STAGE(b, t2 + 2);                   // overwrite with tile t+2
        __builtin_amdgcn_sched_barrier(0);
        MFMA_ALL();
        asm volatile("s_waitcnt vmcnt(8)" ::: "memory");  // tile t+1 landed
        __builtin_amdgcn_sched_barrier(0);
        __builtin_amdgcn_s_barrier();
    }
    // t2 = 30 (buf 0): no further staging
    LOADFRAGS(0);
    MFMA_ALL();
    asm volatile("s_waitcnt vmcnt(0)" ::: "memory");      // tile 31 landed
    __builtin_amdgcn_sched_barrier(0);
    __builtin_amdgcn_s_barrier();
    // t2 = 31 (buf 1)
    LOADFRAGS(1);
    MFMA_ALL();

    const int crow = (l >> 4) * 4;
    const int ccol = l & 15;

    // RoPE epilogue for Q (mat 0, * 0.125*log2e) and K (mat 1), via table
    if (MODE == 0 && mat < 2) {
        const float scale = (mat == 0) ? QSCALE : 1.0f;
        const int odd = ccol & 1;
        int ipair[4];
#pragma unroll
        for (int fn = 0; fn < 4; ++fn)
            ipair[fn] = ((fn * 16 + ccol) >> 1) & 31;     // head-dim pair idx
#pragma unroll
        for (int fm = 0; fm < 8; ++fm)
#pragma unroll
            for (int r = 0; r < 4; ++r) {
                int t = (row0 + fm * 16 + crow + r) & 1023;
                const float2* tb = tbl + (t << 5);
#pragma unroll
                for (int fn = 0; fn < 4; ++fn) {
                    float x = acc[fm][fn][r];
                    float partner = __shfl_xor(x, 1, 64);
                    float2 cs = tb[ipair[fn]];
                    float o = odd ? fmaf(partner, cs.y, x * cs.x)
                                  : fmaf(-partner, cs.y, x * cs.x);
                    acc[fm][fn][r] = o * scale;
                }
            }
    }

#pragma unroll
    for (int fm = 0; fm < 8; ++fm)
#pragma unroll
        for (int fn = 0; fn < 4; ++fn)
#pragma unroll
            for (int r = 0; r < 4; ++r) {
                size_t row = row0 + fm * 16 + crow + r;
                size_t col = col0 + w * 64 + fn * 16 + ccol;
                if (MODE == 0)
                    ((ushort*)Out)[(size_t)mat * 8388608 + row * N + col] =
                        f2bf(acc[fm][fn][r]);
                else
                    ((float*)Out)[row * N + col] = acc[fm][fn][r];
            }
}

// ---------------------------------------------------------------------------
// Flash attention: swapped QK^T, 32x32x16 MFMA, fixed-max exp2 softmax.
// Q pre-scaled by 0.125*log2e. Block = 4 waves x 32 q = 128 q of one (b,h).
// 1D grid 1024, hb-fastest: bid = qt*128 + (h*8+b) -> same-KV blocks on
// one XCD (mod-8 congruent).
// ---------------------------------------------------------------------------
__global__ __launch_bounds__(256, 4)
void attn_bf16_v2(const ushort* __restrict__ Q, const ushort* __restrict__ K,
                  const ushort* __restrict__ V, ushort* __restrict__ O)
{
    __shared__ uint Ksu[64 * 34];     // K tile as u32 pairs, row stride 34 u32
    __shared__ uint Vtu[64 * 34];     // V^T tile: row d, cols key-pairs
    __shared__ uint Os[4][32 * 36];   // per-wave O^T->O transpose buffer

    const int tid = threadIdx.x;
    const int w = tid >> 6, l = tid & 63;
    const int lo = l & 31, hi = l >> 5;
    const int bid = blockIdx.x;
    const int qt = bid >> 7;
    const int hb = bid & 127;
    const int h = hb >> 3, b = hb & 7;
    const int colh = h * 64;

    // Q B-fragments (k = d): lane q = lo, d-chunk kc*16 + hi*8
    const size_t qrow = (size_t)(b * 1024 + qt * 128 + w * 32 + lo);
    bf16x8 qb[4];
#pragma unroll
    for (int kc = 0; kc < 4; ++kc)
        qb[kc] = *(const bf16x8*)&Q[qrow * 1024 + colh + kc * 16 + hi * 8];

    f32x16 acc[2];
#pragma unroll
    for (int i = 0; i < 2; ++i) acc[i] = (f32x16)0.f;
    float lsum = 0.f;

    const size_t kvbase = (size_t)b * 1024 * 1024 + colh;  // + key*1024 + d

    const int skey = tid >> 3, sc = tid & 7;  // K staging
    const int kp = tid & 31, vg = tid >> 5;   // V staging: key pair kp, d-group vg

    for (int kt = 0; kt < 16; ++kt) {
        __syncthreads();
        // stage K [64][68us]: thread covers rows skey, skey+32, 8 d each
#pragma unroll
        for (int u = 0; u < 2; ++u) {
            int key = skey + u * 32;
            uint4 kv = *(const uint4*)&K[kvbase + (size_t)(kt * 64 + key) * 1024 + sc * 8];
            *(uint2*)&Ksu[key * 34 + sc * 4] = make_uint2(kv.x, kv.y);
            *(uint2*)&Ksu[key * 34 + sc * 4 + 2] = make_uint2(kv.z, kv.w);
        }
        // stage V^T: keys 2kp,2kp+1, d = vg*8..+7, packed pairs
        {
            uint4 va = *(const uint4*)&V[kvbase + (size_t)(kt * 64 + 2 * kp) * 1024 + vg * 8];
            uint4 vb = *(const uint4*)&V[kvbase + (size_t)(kt * 64 + 2 * kp + 1) * 1024 + vg * 8];
            const ushort* pa = (const ushort*)&va;
            const ushort* pb = (const ushort*)&vb;
#pragma unroll
            for (int e = 0; e < 8; ++e)
                Vtu[(vg * 8 + e) * 34 + kp] = (uint)pa[e] | ((uint)pb[e] << 16);
        }
        __syncthreads();

        // S^T = K Q^T per 32-key tile; fixed-max exp2 softmax; pack P^T
        uint pw[16];
#pragma unroll
        for (int mt = 0; mt < 2; ++mt) {
            f32x16 s = (f32x16)0.f;
            const int rbase = (mt * 32 + lo) * 34 + hi * 4;
#pragma unroll
            for (int kc = 0; kc < 4; ++kc) {
                union { uint2 d[2]; bf16x8 v; } ak;
                ak.d[0] = *(const uint2*)&Ksu[rbase + kc * 8];
                ak.d[1] = *(const uint2*)&Ksu[rbase + kc * 8 + 2];
                s = __builtin_amdgcn_mfma_f32_32x32x16_bf16(ak.v, qb[kc], s, 0, 0, 0);
            }
            float p[16];
#pragma unroll
            for (int r = 0; r < 16; ++r) {
                p[r] = exp2f(s[r]);
                lsum += p[r];
            }
#pragma unroll
            for (int rp = 0; rp < 8; ++rp)
                pw[mt * 8 + rp] = cvt_pk_bf16(p[2 * rp], p[2 * rp + 1]);
        }

        // build P^T B-fragments in-register via half-wave exchange
        bf16x8 pf[4];
#pragma unroll
        for (int mt = 0; mt < 2; ++mt) {
            uint* W = &pw[mt * 8];
            uint e0 = (uint)__shfl_xor((int)(hi ? W[0] : W[2]), 32);
            uint e1 = (uint)__shfl_xor((int)(hi ? W[1] : W[3]), 32);
            uint e2 = (uint)__shfl_xor((int)(hi ? W[4] : W[6]), 32);
            uint e3 = (uint)__shfl_xor((int)(hi ? W[5] : W[7]), 32);
            union { uint u[4]; bf16x8 v; } f0, f1;
            if (hi == 0) {
                f0.u[0] = W[0]; f0.u[1] = W[1]; f0.u[2] = e0; f0.u[3] = e1;
                f1.u[0] = W[4]; f1.u[1] = W[5]; f1.u[2] = e2; f1.u[3] = e3;
            } else {
                f0.u[0] = e0; f0.u[1] = e1; f0.u[2] = W[2]; f0.u[3] = W[3];
                f1.u[0] = e2; f1.u[1] = e3; f1.u[2] = W[6]; f1.u[3] = W[7];
            }
            pf[mt * 2 + 0] = f0.v;
            pf[mt * 2 + 1] = f1.v;
        }

        // O^T += V^T P^T
#pragma unroll
        for (int dmt = 0; dmt < 2; ++dmt) {
            const int rbase = (dmt * 32 + lo) * 34 + hi * 4;
#pragma unroll
            for (int kcg = 0; kcg < 4; ++kcg) {
                union { uint2 d[2]; bf16x8 v; } vk;
                vk.d[0] = *(const uint2*)&Vtu[rbase + kcg * 8];
                vk.d[1] = *(const uint2*)&Vtu[rbase + kcg * 8 + 2];
                acc[dmt] = __builtin_amdgcn_mfma_f32_32x32x16_bf16(vk.v, pf[kcg], acc[dmt], 0, 0, 0);
            }
        }
    }

    // normalize: row-sum = own half + partner half
    float tot = lsum + __shfl_xor(lsum, 32);
    float inv = 1.0f / tot;

    // O^T -> LDS (bf16 packed pairs), rows q, word cols d/2
    uint* Osw = &Os[w][0];
#pragma unroll
    for (int dmt = 0; dmt < 2; ++dmt)
#pragma unroll
        for (int rp = 0; rp < 8; ++rp) {
            float a0 = acc[dmt][2 * rp] * inv;
            float a1 = acc[dmt][2 * rp + 1] * inv;
            Osw[lo * 36 + dmt * 16 + (rp & 1) + 4 * (rp >> 1) + 2 * hi] =
                cvt_pk_bf16(a0, a1);
        }
    __builtin_amdgcn_s_waitcnt(0);  // lgkm drain before same-wave readback
#pragma unroll
    for (int u = 0; u < 4; ++u) {
        int slot = l + u * 64;
        int qr = slot >> 3, c = slot & 7;
        float4 val = *(const float4*)&Osw[qr * 36 + c * 4];
        *(float4*)&O[(size_t)(b * 1024 + qt * 128 + w * 32 + qr) * 1024 + colh + c * 8] = val;
    }
}

// ---------------------------------------------------------------------------
extern "C" void kernel_launch(void* const* d_in, const int* in_sizes, int n_in,
                              void* d_out, int out_size, void* d_ws, size_t ws_size,
                              hipStream_t stream)
{
    const float* xq  = (const float*)d_in[0];
    const float* xkv = (const float*)d_in[1];
    const float* wq  = (const float*)d_in[2];
    const float* wk  = (const float*)d_in[3];
    const float* wv  = (const float*)d_in[4];
    const float* wo  = (const float*)d_in[5];
    float* out = (float*)d_out;

    ushort* Aq  = (ushort*)d_ws;            // 8M bf16
    ushort* Akv = Aq  + 8388608;
    ushort* WqT = Akv + 8388608;            // 1M each; WqT/WkT/WvT contiguous
    ushort* WkT = WqT + 1048576;
    ushort* WvT = WkT + 1048576;
    ushort* WoT = WvT + 1048576;
    ushort* Qb  = WoT + 1048576;            // 8M each; Qb/Kb/Vb contiguous
    ushort* Kb  = Qb  + 8388608;
    ushort* Vb  = Kb  + 8388608;
    ushort* Ob  = Vb  + 8388608;
    float2* Tbl = (float2*)(Ob + 8388608);  // 32768 float2 = 256 KB

    build_rope_tbl<<<128, 256, 0, stream>>>(Tbl);
    cast_bf16_2<<<dim3(4096, 2), 256, 0, stream>>>(xq, Aq, xkv, Akv);
    transpose_cast_4<<<dim3(32, 32, 4), dim3(32, 8), 0, stream>>>(
        wq, WqT, wk, WkT, wv, WvT, wo, WoT);

    // fused QKV: 3 mats x (64 row-tiles x 8 col-tiles) = 1536 blocks
    gemm8<0><<<1536, 128, 0, stream>>>(Aq, Akv, WqT, Qb, Tbl);

    attn_bf16_v2<<<1024, 256, 0, stream>>>(Qb, Kb, Vb, Ob);

    // out-projection: 64 x 8 = 512 blocks
    gemm8<1><<<512, 128, 0, stream>>>(Ob, nullptr, WoT, out, Tbl);
}